// Round 2
// baseline (877.575 us; speedup 1.0000x reference)
//
#include <hip/hip_runtime.h>

#define NN 50000
#define EE 800000
#define DD 128
#define RR 8
#define CELLS (NN * RR)            // 400000 (rel, dst) cells, key = rel*NN + dst (REL-MAJOR)
#define TILE_N 64
#define NBLK ((NN + TILE_N - 1) / TILE_N)          // 782
#define SCAN_CHUNK 1024
#define SCAN_BLOCKS ((CELLS + SCAN_CHUNK - 1) / SCAN_CHUNK)   // 391

typedef __attribute__((ext_vector_type(4))) float f32x4;
typedef __attribute__((ext_vector_type(8))) short s16x8;
union ABu { uint4 q; s16x8 v; };

// ---------------- bf16 helpers ----------------

__device__ __forceinline__ unsigned int packbf2(float a, float b) {
    unsigned int ua = __float_as_uint(a);
    unsigned int ub = __float_as_uint(b);
    ua = (ua + 0x7fffu + ((ua >> 16) & 1u)) >> 16;           // RNE, low half
    ub = (ub + 0x7fffu + ((ub >> 16) & 1u)) & 0xffff0000u;   // RNE, high half
    return ua | ub;
}

// ---------------- fused prep: to_bf16 + wpack + rpack + count_cells ----------------
#define NB_A ((NN * 32 + 255) / 256)    // 6250: x -> packed bf16 (float4 -> uint2)
#define NB_B 128                        // wpack: 32768 items
#define NB_C 32                         // rpack: 8192 items
#define NB_D ((EE + 255) / 256)         // 3125: count_cells

__global__ void prep_fused(const float* __restrict__ x, unsigned int* __restrict__ xb,
                           const float* __restrict__ W1, const float* __restrict__ W2,
                           unsigned int* __restrict__ Wb1, unsigned int* __restrict__ Wb2,
                           const float* __restrict__ r1, const float* __restrict__ r2,
                           unsigned int* __restrict__ rb1, unsigned int* __restrict__ rb2,
                           const int* __restrict__ dst, const int* __restrict__ et,
                           int* __restrict__ cnt) {
    int bid = blockIdx.x, tid = threadIdx.x;
    if (bid < NB_A) {
        int i = bid * 256 + tid;
        if (i < NN * 32) {
            float4 v = ((const float4*)x)[i];
            ((uint2*)xb)[i] = make_uint2(packbf2(v.x, v.y), packbf2(v.z, v.w));
        }
    } else if (bid < NB_A + NB_B) {
        // W [16 blocks of 64x64, row-major (k,n)] -> Wb [block][n][kp]
        int i = (bid - NB_A) * 256 + tid;
        int kp = i & 31, n = (i >> 5) & 63, rb = i >> 11;
        int s0 = (rb * 64 + 2 * kp) * 64 + n;
        int s1 = (rb * 64 + 2 * kp + 1) * 64 + n;
        Wb1[((rb * 64 + n) * 32) + kp] = packbf2(W1[s0], W1[s1]);
        Wb2[((rb * 64 + n) * 32) + kp] = packbf2(W2[s0], W2[s1]);
    } else if (bid < NB_A + NB_B + NB_C) {
        // root [128k x 128n] -> rb [n][kp]
        int i = (bid - NB_A - NB_B) * 256 + tid;
        int kp = i & 63, n = i >> 6;
        int s0 = (2 * kp) * 128 + n, s1 = (2 * kp + 1) * 128 + n;
        rb1[n * 64 + kp] = packbf2(r1[s0], r1[s1]);
        rb2[n * 64 + kp] = packbf2(r2[s0], r2[s1]);
    } else {
        int e = (bid - NB_A - NB_B - NB_C) * 256 + tid;
        if (e < EE) atomicAdd(&cnt[et[e] * NN + dst[e]], 1);
    }
}

// ---------------- prep: scans + scatter (CSR by cell = rel*NN + dst) ----------------

__global__ __launch_bounds__(256) void scan1(const int* __restrict__ cnt,
                                             int* __restrict__ off, int* __restrict__ bsum) {
    __shared__ int s[256];
    int tid = threadIdx.x;
    int base = blockIdx.x * SCAN_CHUNK + tid * 4;
    int v[4];
#pragma unroll
    for (int i = 0; i < 4; ++i) v[i] = (base + i < CELLS) ? cnt[base + i] : 0;
    int tot = v[0] + v[1] + v[2] + v[3];
    s[tid] = tot;
    __syncthreads();
    for (int d = 1; d < 256; d <<= 1) {
        int t = (tid >= d) ? s[tid - d] : 0;
        __syncthreads();
        s[tid] += t;
        __syncthreads();
    }
    int excl = s[tid] - tot;
    if (tid == 255) bsum[blockIdx.x] = s[255];
    int run = excl;
#pragma unroll
    for (int i = 0; i < 4; ++i) {
        if (base + i < CELLS) off[base + i] = run;
        run += v[i];
    }
}

// merged scan2+scan3: each block reduces its own chunk-prefix from bsum, then finalizes
__global__ __launch_bounds__(256) void scan3(int* __restrict__ off, const int* __restrict__ bsum,
                                             int* __restrict__ cur) {
    __shared__ int red[256];
    int tid = threadIdx.x, bid = blockIdx.x;
    int a = 0;
    for (int i = tid; i < bid; i += 256) a += bsum[i];
    red[tid] = a;
    __syncthreads();
#pragma unroll
    for (int d = 128; d > 0; d >>= 1) {
        if (tid < d) red[tid] += red[tid + d];
        __syncthreads();
    }
    int add = red[0];
    int base = bid * SCAN_CHUNK + tid * 4;
#pragma unroll
    for (int i = 0; i < 4; ++i) {
        int c = base + i;
        if (c < CELLS) {
            int o = off[c] + add;
            off[c] = o;
            cur[c] = o;
        }
    }
    if (bid == 0 && tid == 0) off[CELLS] = EE;   // sentinel
}

// scatter: per-edge record (src<<6 | dst&63, 1/cnt) sorted by cell.
// dst&63 is the node's local row in its tile because TILE_N == 64 and tiles are aligned.
__global__ void cell_scatter(const int* __restrict__ src, const int* __restrict__ dst,
                             const int* __restrict__ et, int* __restrict__ cur,
                             const int* __restrict__ cnt, uint2* __restrict__ epack) {
    int e = blockIdx.x * blockDim.x + threadIdx.x;
    if (e < EE) {
        int d = dst[e];
        int cell = et[e] * NN + d;
        int pos = atomicAdd(&cur[cell], 1);
        float sc = 1.0f / (float)cnt[cell];
        epack[pos] = make_uint2(((unsigned int)src[e] << 6) | (unsigned int)(d & 63),
                                __float_as_uint(sc));
    }
}

// ---------------- fused layer, MFMA GEMM ----------------
// Gather v3: EDGE-PARALLEL with LDS fp32 atomic accumulation.
//   One wave iteration = one edge: 64 lanes load the 256B bf16 row (coalesced),
//   pre-scale by 1/cnt (carried per-edge), ds_add_f32 into ACC[node][feat].
//   Contiguous per-wave quarter-ranges + in-register run-combining of same-cell
//   edges (wave-uniform compare) halve the atomic count. No serial boundary walk.
// Per relation: accumulate -> barrier -> convert ACC->packed bf16 MT (re-zero ACC)
//   -> barrier -> MFMA.  mfma(r) overlaps gather(r+1) across waves (MT vs ACC disjoint).
// LDS: MT 64x67 uint (17.2KB, stride 67 -> conflict-free) + ACC 64x130 f32 (33.3KB,
//   reused as epilogue OUT) = 50.4KB -> 3 blocks/CU, 12 waves/CU, no spills.
template <int RELU, int WRITEF, int WRITEB>
__global__ __launch_bounds__(256, 3) void layer_fused(
    const unsigned int* __restrict__ xgb, const uint2* __restrict__ epck,
    const int* __restrict__ off,
    const unsigned int* __restrict__ Wb, const unsigned int* __restrict__ rootb,
    const float* __restrict__ bias, float* __restrict__ outf,
    unsigned int* __restrict__ outb) {

    __shared__ unsigned int MT[64 * 67];     // packed bf16 A-tile [kpair][node]
    __shared__ float ACC[64 * 130];          // fp32 accum [node][feat]; also epilogue OUT

    int tid = threadIdx.x;
    int n0 = blockIdx.x * TILE_N;
    int w = tid >> 6, l = tid & 63;
    int quad = l >> 4, li = l & 15;
    int b = w >> 1;                          // out-half this wave serves

    f32x4 acc[4][2];
#pragma unroll
    for (int s = 0; s < 2; ++s) {
        float bb = bias[32 * w + 16 * s + li];
#pragma unroll
        for (int mt = 0; mt < 4; ++mt) {
            acc[mt][s][0] = bb; acc[mt][s][1] = bb; acc[mt][s][2] = bb; acc[mt][s][3] = bb;
        }
    }

    // zero ACC (feature pairs 2l,2l+1 of node rows 4i+w)
#pragma unroll
    for (int i = 0; i < 16; ++i)
        *(float2*)&ACC[(4 * i + w) * 130 + 2 * l] = make_float2(0.f, 0.f);
    __syncthreads();

    int nend = n0 + TILE_N; if (nend > NN) nend = NN;

    for (int r = 0; r < RR; ++r) {
        // ---- edge-parallel gather-mean into ACC ----
        int obeg = off[r * NN + n0];
        int oend = off[r * NN + nend];
        int total = oend - obeg;
        int per = (total + 3) >> 2;              // contiguous quarter per wave
        int t0 = obeg + w * per;
        int t1 = t0 + per;
        if (t0 > oend) t0 = oend;
        if (t1 > oend) t1 = oend;

        float c0 = 0.f, c1 = 0.f;
        int prevnl = -1;
        for (int t = t0; t < t1; t += 8) {
            int m = t1 - t; if (m > 8) m = 8;
            uint2 ep[8];
#pragma unroll
            for (int j = 0; j < 8; ++j) if (j < m) ep[j] = epck[t + j];        // broadcast
            unsigned int u[8];
#pragma unroll
            for (int j = 0; j < 8; ++j) if (j < m)
                u[j] = xgb[(ep[j].x & 0xffffffc0u) + (unsigned)l];             // 256B/wave
#pragma unroll
            for (int j = 0; j < 8; ++j) if (j < m) {
                int nl = (int)(ep[j].x & 63u);                                 // wave-uniform
                float sc = __uint_as_float(ep[j].y);
                if (nl != prevnl) {                                            // uniform branch
                    if (prevnl >= 0) {
                        atomicAdd(&ACC[prevnl * 130 + 2 * l], c0);
                        atomicAdd(&ACC[prevnl * 130 + 2 * l + 1], c1);
                    }
                    c0 = 0.f; c1 = 0.f; prevnl = nl;
                }
                c0 += __uint_as_float(u[j] << 16) * sc;
                c1 += __uint_as_float(u[j] & 0xffff0000u) * sc;
            }
        }
        if (prevnl >= 0) {
            atomicAdd(&ACC[prevnl * 130 + 2 * l], c0);
            atomicAdd(&ACC[prevnl * 130 + 2 * l + 1], c1);
        }
        __syncthreads();

        // ---- convert ACC -> MT (packed bf16, [kpair][node] stride 67), re-zero ACC ----
#pragma unroll
        for (int i = 0; i < 16; ++i) {
            int n = 4 * i + w;                                   // wave-uniform node
            float2 v = *(float2*)&ACC[n * 130 + 2 * l];
            MT[l * 67 + n] = packbf2(v.x, v.y);
            *(float2*)&ACC[n * 130 + 2 * l] = make_float2(0.f, 0.f);
        }
        __syncthreads();

        // ---- block-diag GEMM: 16 mfma/wave; A from MT, B from global Wb (L1-hot) ----
        const uint4* WbB = (const uint4*)(Wb + (((size_t)r * 2 + b) * 64) * 32);
        int nl0 = (w & 1) * 32 + li;
#pragma unroll
        for (int kc = 0; kc < 2; ++kc) {
            ABu bf0, bf1;
            bf0.q = WbB[nl0 * 8 + 4 * kc + quad];
            bf1.q = WbB[(nl0 + 16) * 8 + 4 * kc + quad];
#pragma unroll
            for (int mt = 0; mt < 4; ++mt) {
                ABu af;
                int base = (32 * b + 16 * kc + 4 * quad) * 67 + 16 * mt + li;
                af.q.x = MT[base]; af.q.y = MT[base + 67];
                af.q.z = MT[base + 134]; af.q.w = MT[base + 201];
                acc[mt][0] = __builtin_amdgcn_mfma_f32_16x16x32_bf16(af.v, bf0.v, acc[mt][0], 0, 0, 0);
                acc[mt][1] = __builtin_amdgcn_mfma_f32_16x16x32_bf16(af.v, bf1.v, acc[mt][1], 0, 0, 0);
            }
        }
        // no barrier: gather(r+1) touches only ACC; convert(r+1) is after the next
        // barrier, which every wave reaches only after finishing mfma(r).
    }
    __syncthreads();    // all waves done mfma(7) before MT is overwritten

    // ---- root term: MT <- own row (already packed bf16: direct copy) ----
    {
        int node = n0 + l;
        if (node < NN) {
            const uint4* xr = (const uint4*)(xgb + (size_t)node * 64 + w * 16);
            uint4 X[4] = {xr[0], xr[1], xr[2], xr[3]};
#pragma unroll
            for (int i = 0; i < 4; ++i) {
                MT[(16 * w + 4 * i + 0) * 67 + l] = X[i].x;
                MT[(16 * w + 4 * i + 1) * 67 + l] = X[i].y;
                MT[(16 * w + 4 * i + 2) * 67 + l] = X[i].z;
                MT[(16 * w + 4 * i + 3) * 67 + l] = X[i].w;
            }
        } else {
#pragma unroll
            for (int i = 0; i < 16; ++i) MT[(16 * w + i) * 67 + l] = 0u;
        }
    }
    __syncthreads();

    // root GEMM: K=128 -> 4 k-chunks, 32 mfma/wave
    const uint4* RbB = (const uint4*)rootb;
#pragma unroll
    for (int kc = 0; kc < 4; ++kc) {
        ABu bf0, bf1;
        bf0.q = RbB[(32 * w + li) * 16 + 4 * kc + quad];
        bf1.q = RbB[(32 * w + 16 + li) * 16 + 4 * kc + quad];
#pragma unroll
        for (int mt = 0; mt < 4; ++mt) {
            ABu af;
            int base = (16 * kc + 4 * quad) * 67 + 16 * mt + li;
            af.q.x = MT[base]; af.q.y = MT[base + 67];
            af.q.z = MT[base + 134]; af.q.w = MT[base + 201];
            acc[mt][0] = __builtin_amdgcn_mfma_f32_16x16x32_bf16(af.v, bf0.v, acc[mt][0], 0, 0, 0);
            acc[mt][1] = __builtin_amdgcn_mfma_f32_16x16x32_bf16(af.v, bf1.v, acc[mt][1], 0, 0, 0);
        }
    }
    __syncthreads();

    // ---- epilogue: stage D to LDS (fp32, stride 130, in ACC region), coalesced stores ----
    float* OF = ACC;
#pragma unroll
    for (int mt = 0; mt < 4; ++mt)
#pragma unroll
        for (int s = 0; s < 2; ++s)
#pragma unroll
            for (int reg = 0; reg < 4; ++reg)
                OF[(16 * mt + 4 * quad + reg) * 130 + 32 * w + 16 * s + li] = acc[mt][s][reg];
    __syncthreads();

    if (WRITEB) {
        int p = tid & 63, rg = tid >> 6;     // pair-col, row-group (4 rows/pass)
#pragma unroll 4
        for (int it = 0; it < 16; ++it) {
            int ee = it * 4 + rg, row = n0 + ee;
            if (row < NN) {
                float v0 = OF[ee * 130 + 2 * p], v1 = OF[ee * 130 + 2 * p + 1];
                if (RELU) { v0 = fmaxf(v0, 0.f); v1 = fmaxf(v1, 0.f); }
                outb[(size_t)row * 64 + p] = packbf2(v0, v1);
            }
        }
    }
    if (WRITEF) {
        int d4 = (tid & 31) * 4, rg = tid >> 5;   // 8 rows/pass
#pragma unroll 4
        for (int it = 0; it < 8; ++it) {
            int ee = it * 8 + rg, row = n0 + ee;
            if (row < NN) {
                float4 v = make_float4(OF[ee * 130 + d4], OF[ee * 130 + d4 + 1],
                                       OF[ee * 130 + d4 + 2], OF[ee * 130 + d4 + 3]);
                if (RELU) {
                    v.x = fmaxf(v.x, 0.f); v.y = fmaxf(v.y, 0.f);
                    v.z = fmaxf(v.z, 0.f); v.w = fmaxf(v.w, 0.f);
                }
                *(float4*)(outf + (size_t)row * DD + d4) = v;
            }
        }
    }
}

// ---------------- driver ----------------

extern "C" void kernel_launch(void* const* d_in, const int* in_sizes, int n_in,
                              void* d_out, int out_size, void* d_ws, size_t ws_size,
                              hipStream_t stream) {
    const float* x     = (const float*)d_in[0];
    const int*   ei    = (const int*)d_in[1];
    const int*   src   = ei;
    const int*   dstp  = ei + EE;
    const int*   et    = (const int*)d_in[2];
    const float* W1    = (const float*)d_in[3];
    const float* root1 = (const float*)d_in[4];
    const float* b1    = (const float*)d_in[5];
    const float* W2    = (const float*)d_in[6];
    const float* root2 = (const float*)d_in[7];
    const float* b2    = (const float*)d_in[8];
    float* out = (float*)d_out;

    // ws layout (4 B elements)
    unsigned int* xb  = (unsigned int*)d_ws;         // NN*64 packed bf16 pairs
    unsigned int* hb  = xb + (size_t)NN * 64;        // NN*64
    int* cnt  = (int*)(hb + (size_t)NN * 64);        // CELLS
    int* off  = cnt + CELLS;                         // CELLS + 1
    int* cur  = off + CELLS + 1;                     // CELLS
    int* bsum = cur + CELLS;                         // 512 (+1 pad for 8B alignment)
    uint2* epack = (uint2*)(bsum + 513);             // EE uint2 (8B-aligned)
    unsigned int* Wb1 = (unsigned int*)(epack + EE); // 32768
    unsigned int* Wb2 = Wb1 + 32768;                 // 32768
    unsigned int* rb1 = Wb2 + 32768;                 // 8192
    unsigned int* rb2 = rb1 + 8192;                  // 8192

    hipMemsetAsync(cnt, 0, CELLS * sizeof(int), stream);
    prep_fused<<<NB_A + NB_B + NB_C + NB_D, 256, 0, stream>>>(
        x, xb, W1, W2, Wb1, Wb2, root1, root2, rb1, rb2, dstp, et, cnt);
    scan1<<<SCAN_BLOCKS, 256, 0, stream>>>(cnt, off, bsum);
    scan3<<<SCAN_BLOCKS, 256, 0, stream>>>(off, bsum, cur);
    cell_scatter<<<(EE + 255) / 256, 256, 0, stream>>>(src, dstp, et, cur, cnt, epack);

    // layer 1: bf16 h out;  layer 2: fp32 out
    layer_fused<1, 0, 1><<<NBLK, 256, 0, stream>>>(xb, epack, off, Wb1, rb1, b1,
                                                   nullptr, hb);
    layer_fused<0, 1, 0><<<NBLK, 256, 0, stream>>>(hb, epack, off, Wb2, rb2, b2,
                                                   out, nullptr);
}

// Round 3
// 366.467 us; speedup vs baseline: 2.3947x; 2.3947x over previous
//
#include <hip/hip_runtime.h>

#define NN 50000
#define EE 800000
#define DD 128
#define RR 8
#define CELLS (NN * RR)            // 400000 (rel, dst) cells, key = rel*NN + dst (REL-MAJOR)
#define TILE_N 64
#define NBLK ((NN + TILE_N - 1) / TILE_N)          // 782
#define SCAN_CHUNK 1024
#define SCAN_BLOCKS ((CELLS + SCAN_CHUNK - 1) / SCAN_CHUNK)   // 391

typedef __attribute__((ext_vector_type(4))) float f32x4;
typedef __attribute__((ext_vector_type(8))) short s16x8;
union ABu { uint4 q; s16x8 v; };

// ---------------- bf16 helpers ----------------

__device__ __forceinline__ unsigned int packbf2(float a, float b) {
    unsigned int ua = __float_as_uint(a);
    unsigned int ub = __float_as_uint(b);
    ua = (ua + 0x7fffu + ((ua >> 16) & 1u)) >> 16;           // RNE, low half
    ub = (ub + 0x7fffu + ((ub >> 16) & 1u)) & 0xffff0000u;   // RNE, high half
    return ua | ub;
}

// unpack 2 uint4 (16 bf16) and add into sA[0..15]
__device__ __forceinline__ void upadd16(float* sA, uint4 a, uint4 b) {
    unsigned int u[8] = {a.x, a.y, a.z, a.w, b.x, b.y, b.z, b.w};
#pragma unroll
    for (int j = 0; j < 8; ++j) {
        sA[2 * j]     += __uint_as_float(u[j] << 16);
        sA[2 * j + 1] += __uint_as_float(u[j] & 0xffff0000u);
    }
}

// ---------------- fused prep: to_bf16 + wpack + rpack + count_cells ----------------
#define NB_A ((NN * 32 + 255) / 256)    // 6250: x -> packed bf16 (float4 -> uint2)
#define NB_B 128                        // wpack: 32768 items
#define NB_C 32                         // rpack: 8192 items
#define NB_D ((EE + 255) / 256)         // 3125: count_cells

__global__ void prep_fused(const float* __restrict__ x, unsigned int* __restrict__ xb,
                           const float* __restrict__ W1, const float* __restrict__ W2,
                           unsigned int* __restrict__ Wb1, unsigned int* __restrict__ Wb2,
                           const float* __restrict__ r1, const float* __restrict__ r2,
                           unsigned int* __restrict__ rb1, unsigned int* __restrict__ rb2,
                           const int* __restrict__ dst, const int* __restrict__ et,
                           int* __restrict__ cnt) {
    int bid = blockIdx.x, tid = threadIdx.x;
    if (bid < NB_A) {
        int i = bid * 256 + tid;
        if (i < NN * 32) {
            float4 v = ((const float4*)x)[i];
            ((uint2*)xb)[i] = make_uint2(packbf2(v.x, v.y), packbf2(v.z, v.w));
        }
    } else if (bid < NB_A + NB_B) {
        // W [16 blocks of 64x64, row-major (k,n)] -> Wb [block][n][kp]
        int i = (bid - NB_A) * 256 + tid;
        int kp = i & 31, n = (i >> 5) & 63, rb = i >> 11;
        int s0 = (rb * 64 + 2 * kp) * 64 + n;
        int s1 = (rb * 64 + 2 * kp + 1) * 64 + n;
        Wb1[((rb * 64 + n) * 32) + kp] = packbf2(W1[s0], W1[s1]);
        Wb2[((rb * 64 + n) * 32) + kp] = packbf2(W2[s0], W2[s1]);
    } else if (bid < NB_A + NB_B + NB_C) {
        // root [128k x 128n] -> rb [n][kp]
        int i = (bid - NB_A - NB_B) * 256 + tid;
        int kp = i & 63, n = i >> 6;
        int s0 = (2 * kp) * 128 + n, s1 = (2 * kp + 1) * 128 + n;
        rb1[n * 64 + kp] = packbf2(r1[s0], r1[s1]);
        rb2[n * 64 + kp] = packbf2(r2[s0], r2[s1]);
    } else {
        int e = (bid - NB_A - NB_B - NB_C) * 256 + tid;
        if (e < EE) atomicAdd(&cnt[et[e] * NN + dst[e]], 1);
    }
}

// ---------------- prep: scans + scatter (CSR by cell = rel*NN + dst) ----------------

__global__ __launch_bounds__(256) void scan1(const int* __restrict__ cnt,
                                             int* __restrict__ off, int* __restrict__ bsum) {
    __shared__ int s[256];
    int tid = threadIdx.x;
    int base = blockIdx.x * SCAN_CHUNK + tid * 4;
    int v[4];
#pragma unroll
    for (int i = 0; i < 4; ++i) v[i] = (base + i < CELLS) ? cnt[base + i] : 0;
    int tot = v[0] + v[1] + v[2] + v[3];
    s[tid] = tot;
    __syncthreads();
    for (int d = 1; d < 256; d <<= 1) {
        int t = (tid >= d) ? s[tid - d] : 0;
        __syncthreads();
        s[tid] += t;
        __syncthreads();
    }
    int excl = s[tid] - tot;
    if (tid == 255) bsum[blockIdx.x] = s[255];
    int run = excl;
#pragma unroll
    for (int i = 0; i < 4; ++i) {
        if (base + i < CELLS) off[base + i] = run;
        run += v[i];
    }
}

// merged scan2+scan3: each block reduces its own chunk-prefix from bsum, then finalizes
__global__ __launch_bounds__(256) void scan3(int* __restrict__ off, const int* __restrict__ bsum,
                                             int* __restrict__ cur) {
    __shared__ int red[256];
    int tid = threadIdx.x, bid = blockIdx.x;
    int a = 0;
    for (int i = tid; i < bid; i += 256) a += bsum[i];
    red[tid] = a;
    __syncthreads();
#pragma unroll
    for (int d = 128; d > 0; d >>= 1) {
        if (tid < d) red[tid] += red[tid + d];
        __syncthreads();
    }
    int add = red[0];
    int base = bid * SCAN_CHUNK + tid * 4;
#pragma unroll
    for (int i = 0; i < 4; ++i) {
        int c = base + i;
        if (c < CELLS) {
            int o = off[c] + add;
            off[c] = o;
            cur[c] = o;
        }
    }
    if (bid == 0 && tid == 0) off[CELLS] = EE;   // sentinel
}

__global__ void cell_scatter(const int* __restrict__ src, const int* __restrict__ dst,
                             const int* __restrict__ et, int* __restrict__ cur,
                             int* __restrict__ esrc) {
    int e = blockIdx.x * blockDim.x + threadIdx.x;
    if (e < EE) {
        int cell = et[e] * NN + dst[e];
        int pos = atomicAdd(&cur[cell], 1);
        esrc[pos] = src[e];
    }
}

// ---------------- fused layer, MFMA GEMM ----------------
// Round-0 gather structure (lane = node, per-thread fp32 accumulation, edge-parallel
// across lanes) but with 512-thread blocks: 64 nodes x 8 k-eighths -> sA[16] per
// thread (was 32), 2x uint4 row loads per edge (was 4).  MFMA: 8 waves, each owns
// 16 output cols -> acc = 4x f32x4 (16 VGPR, was 32).  Live state ~90 VGPR: no spill
// at __launch_bounds__(512,4) (128-VGPR cap, 2 blocks/CU = 16 waves/CU).
// Pipelining via barrier placement: gather-loads(r) | bar | MT-write(r) | bar | mfma(r)
// -> the long divergent-load phase of r overlaps other waves' mfma(r-1).
// LDS: union { MT[64 kpair][67] uint 17.2KB, OF[64][130] f32 33.3KB } = 33.3KB.
template <int RELU, int WRITEF, int WRITEB>
__global__ __launch_bounds__(512, 4) void layer_fused(
    const unsigned int* __restrict__ xgb, const int* __restrict__ esrc,
    const int* __restrict__ off,
    const unsigned int* __restrict__ Wb, const unsigned int* __restrict__ rootb,
    const float* __restrict__ bias, float* __restrict__ outf,
    unsigned int* __restrict__ outb) {

    __shared__ unsigned int SH[8320];        // 33280 B union
    unsigned int* MT = SH;                   // packed bf16 A-tile [kpair][67]

    int tid = threadIdx.x;
    int n0 = blockIdx.x * TILE_N;
    int e = tid & 63, q = tid >> 6;          // gather: lane-node, k-eighth (16 feats)
    int w = tid >> 6, l = tid & 63;          // gemm: wave (0..7), lane
    int quad = l >> 4, li = l & 15;
    int b = w >> 2;                          // block (out-half) this wave serves

    f32x4 acc[4];
    {
        float bb = bias[16 * w + li];
#pragma unroll
        for (int mt = 0; mt < 4; ++mt) {
            acc[mt][0] = bb; acc[mt][1] = bb; acc[mt][2] = bb; acc[mt][3] = bb;
        }
    }

    int node = n0 + e;

    for (int r = 0; r < RR; ++r) {
        // ---- gather mean (bf16 payload, fp32 accum); thread owns 16 feats of node ----
        float sA[16];
#pragma unroll
        for (int i = 0; i < 16; ++i) sA[i] = 0.f;
        int ne = 0;
        if (node < NN) {
            int cell = r * NN + node;
            int o = off[cell];
            ne = off[cell + 1] - o;
            int t2 = 0;
            for (; t2 + 2 <= ne; t2 += 2) {
                int s0 = esrc[o + t2], s1 = esrc[o + t2 + 1];
                const uint4* p0 = (const uint4*)(xgb + (size_t)s0 * 64 + q * 8);
                const uint4* p1 = (const uint4*)(xgb + (size_t)s1 * 64 + q * 8);
                uint4 A0 = p0[0], A1 = p0[1];
                uint4 B0 = p1[0], B1 = p1[1];
                upadd16(sA, A0, A1);
                upadd16(sA, B0, B1);
            }
            if (t2 < ne) {
                int s0 = esrc[o + t2];
                const uint4* p0 = (const uint4*)(xgb + (size_t)s0 * 64 + q * 8);
                uint4 A0 = p0[0], A1 = p0[1];
                upadd16(sA, A0, A1);
            }
        }
        float sc = 1.0f / (float)max(ne, 1);

        __syncthreads();                     // everyone past mfma(r-1): MT reusable
#pragma unroll
        for (int i = 0; i < 8; ++i)
            MT[(8 * q + i) * 67 + e] = packbf2(sA[2 * i] * sc, sA[2 * i + 1] * sc);
        __syncthreads();

        // ---- block-diag GEMM: 8 mfma/wave; A from MT, B from global Wb (L1-hot) ----
        const uint4* WbB = (const uint4*)(Wb + (((size_t)r * 2 + b) * 64) * 32);
        int nloc = (w & 3) * 16 + li;        // out-col within block
#pragma unroll
        for (int kc = 0; kc < 2; ++kc) {
            ABu bf;
            bf.q = WbB[nloc * 8 + 4 * kc + quad];
#pragma unroll
            for (int mt = 0; mt < 4; ++mt) {
                ABu af;
                int base = (32 * b + 16 * kc + 4 * quad) * 67 + 16 * mt + li;
                af.q.x = MT[base]; af.q.y = MT[base + 67];
                af.q.z = MT[base + 134]; af.q.w = MT[base + 201];
                acc[mt] = __builtin_amdgcn_mfma_f32_16x16x32_bf16(af.v, bf.v, acc[mt], 0, 0, 0);
            }
        }
    }
    __syncthreads();     // all waves done mfma(7) before MT overwrite

    // ---- root term: MT <- own row (already packed bf16: direct copy) ----
    if (node < NN) {
        const uint4* xr = (const uint4*)(xgb + (size_t)node * 64 + q * 8);
        uint4 X0 = xr[0], X1 = xr[1];
        MT[(8 * q + 0) * 67 + e] = X0.x;
        MT[(8 * q + 1) * 67 + e] = X0.y;
        MT[(8 * q + 2) * 67 + e] = X0.z;
        MT[(8 * q + 3) * 67 + e] = X0.w;
        MT[(8 * q + 4) * 67 + e] = X1.x;
        MT[(8 * q + 5) * 67 + e] = X1.y;
        MT[(8 * q + 6) * 67 + e] = X1.z;
        MT[(8 * q + 7) * 67 + e] = X1.w;
    } else {
#pragma unroll
        for (int i = 0; i < 8; ++i) MT[(8 * q + i) * 67 + e] = 0u;
    }
    __syncthreads();

    // root GEMM: K=128 -> 4 k-chunks, 16 mfma/wave
    const uint4* RbB = (const uint4*)rootb;
#pragma unroll
    for (int kc = 0; kc < 4; ++kc) {
        ABu bf;
        bf.q = RbB[(16 * w + li) * 16 + 4 * kc + quad];
#pragma unroll
        for (int mt = 0; mt < 4; ++mt) {
            ABu af;
            int base = (16 * kc + 4 * quad) * 67 + 16 * mt + li;
            af.q.x = MT[base]; af.q.y = MT[base + 67];
            af.q.z = MT[base + 134]; af.q.w = MT[base + 201];
            acc[mt] = __builtin_amdgcn_mfma_f32_16x16x32_bf16(af.v, bf.v, acc[mt], 0, 0, 0);
        }
    }
    __syncthreads();

    // ---- epilogue: stage D to LDS (fp32, stride 130), then coalesced stores ----
    float* OF = (float*)SH;
#pragma unroll
    for (int mt = 0; mt < 4; ++mt)
#pragma unroll
        for (int reg = 0; reg < 4; ++reg)
            OF[(16 * mt + 4 * quad + reg) * 130 + 16 * w + li] = acc[mt][reg];
    __syncthreads();

    if (WRITEB) {
        int p = tid & 63, rg = tid >> 6;     // pair-col, row-group (8 rows/pass)
#pragma unroll 4
        for (int it = 0; it < 8; ++it) {
            int ee = it * 8 + rg, row = n0 + ee;
            if (row < NN) {
                float v0 = OF[ee * 130 + 2 * p], v1 = OF[ee * 130 + 2 * p + 1];
                if (RELU) { v0 = fmaxf(v0, 0.f); v1 = fmaxf(v1, 0.f); }
                outb[(size_t)row * 64 + p] = packbf2(v0, v1);
            }
        }
    }
    if (WRITEF) {
        int d4 = (tid & 31) * 4, rg = tid >> 5;   // 16 rows/pass
#pragma unroll 4
        for (int it = 0; it < 4; ++it) {
            int ee = it * 16 + rg, row = n0 + ee;
            if (row < NN) {
                float4 v = make_float4(OF[ee * 130 + d4], OF[ee * 130 + d4 + 1],
                                       OF[ee * 130 + d4 + 2], OF[ee * 130 + d4 + 3]);
                if (RELU) {
                    v.x = fmaxf(v.x, 0.f); v.y = fmaxf(v.y, 0.f);
                    v.z = fmaxf(v.z, 0.f); v.w = fmaxf(v.w, 0.f);
                }
                *(float4*)(outf + (size_t)row * DD + d4) = v;
            }
        }
    }
}

// ---------------- driver ----------------

extern "C" void kernel_launch(void* const* d_in, const int* in_sizes, int n_in,
                              void* d_out, int out_size, void* d_ws, size_t ws_size,
                              hipStream_t stream) {
    const float* x     = (const float*)d_in[0];
    const int*   ei    = (const int*)d_in[1];
    const int*   src   = ei;
    const int*   dstp  = ei + EE;
    const int*   et    = (const int*)d_in[2];
    const float* W1    = (const float*)d_in[3];
    const float* root1 = (const float*)d_in[4];
    const float* b1    = (const float*)d_in[5];
    const float* W2    = (const float*)d_in[6];
    const float* root2 = (const float*)d_in[7];
    const float* b2    = (const float*)d_in[8];
    float* out = (float*)d_out;

    // ws layout (4 B elements)
    unsigned int* xb  = (unsigned int*)d_ws;         // NN*64 packed bf16 pairs
    unsigned int* hb  = xb + (size_t)NN * 64;        // NN*64
    int* cnt  = (int*)(hb + (size_t)NN * 64);        // CELLS
    int* off  = cnt + CELLS;                         // CELLS + 1
    int* cur  = off + CELLS + 1;                     // CELLS
    int* bsum = cur + CELLS;                         // 512
    int* esrc = bsum + 512;                          // EE
    unsigned int* Wb1 = (unsigned int*)(esrc + EE);  // 32768
    unsigned int* Wb2 = Wb1 + 32768;                 // 32768
    unsigned int* rb1 = Wb2 + 32768;                 // 8192
    unsigned int* rb2 = rb1 + 8192;                  // 8192

    hipMemsetAsync(cnt, 0, CELLS * sizeof(int), stream);
    prep_fused<<<NB_A + NB_B + NB_C + NB_D, 256, 0, stream>>>(
        x, xb, W1, W2, Wb1, Wb2, root1, root2, rb1, rb2, dstp, et, cnt);
    scan1<<<SCAN_BLOCKS, 256, 0, stream>>>(cnt, off, bsum);
    scan3<<<SCAN_BLOCKS, 256, 0, stream>>>(off, bsum, cur);
    cell_scatter<<<(EE + 255) / 256, 256, 0, stream>>>(src, dstp, et, cur, esrc);

    // layer 1: bf16 h out;  layer 2: fp32 out
    layer_fused<1, 0, 1><<<NBLK, 512, 0, stream>>>(xb, esrc, off, Wb1, rb1, b1,
                                                   nullptr, hb);
    layer_fused<0, 1, 0><<<NBLK, 512, 0, stream>>>(hb, esrc, off, Wb2, rb2, b2,
                                                   out, nullptr);
}